// Round 9
// baseline (213.978 us; speedup 1.0000x reference)
//
#include <hip/hip_runtime.h>
#include <hip/hip_bf16.h>
#include <stdint.h>

// Problem constants
#define BATCH 4
#define SEQ   1024
#define EMB   1024
#define NHEAD 16
#define HDIM  64
#define MTOT  (BATCH*SEQ)          // 4096 rows
#define MELEM (MTOT*EMB)           // 4,194,304 elements per [B,S,E] tensor

typedef __attribute__((ext_vector_type(8))) short short8;
typedef __attribute__((ext_vector_type(4))) float f32x4;
typedef __attribute__((ext_vector_type(4))) unsigned short us4;

// fast f32->bf16: round-half-up via integer add (inputs finite, no NaN).
static __device__ __forceinline__ unsigned short f2bf_fast(float f) {
  unsigned u = __builtin_bit_cast(unsigned, f);
  return (unsigned short)((u + 0x8000u) >> 16);
}

// async global->LDS, 16B per lane. lds ptr must be WAVE-UNIFORM base;
// HW scatters lane i to base + i*16. (m97 recipe)
static __device__ __forceinline__ void cp16(const void* g, const void* lds_uniform) {
  __builtin_amdgcn_global_load_lds(
      (const __attribute__((address_space(1))) unsigned int*)(uintptr_t)g,
      (__attribute__((address_space(3))) unsigned int*)(unsigned int)(uintptr_t)lds_uniform,
      16, 0, 0);
}

// ---------------------------------------------------------------- convert f32 -> bf16 (Re & Im fused)
__global__ __launch_bounds__(256) void cvt_bf16(const float* __restrict__ in0,
                                                const float* __restrict__ in1,
                                                short* __restrict__ out0,
                                                short* __restrict__ out1) {
  const float* in  = blockIdx.y ? in1  : in0;
  short*       out = blockIdx.y ? out1 : out0;
  int i = blockIdx.x * 256 + threadIdx.x;   // each thread: 4 elements
  float4 f = ((const float4*)in)[i];
  unsigned r0 = ((unsigned)f2bf_fast(f.y) << 16) | f2bf_fast(f.x);
  unsigned r1 = ((unsigned)f2bf_fast(f.w) << 16) | f2bf_fast(f.z);
  ((uint2*)out)[i] = make_uint2(r0, r1);
}

// ---------------------------------------------------- transpose+convert W[k][n] -> Wt[n][k] bf16 (x4 fused)
__global__ __launch_bounds__(256) void wtrans(const float* __restrict__ W0,
                                              const float* __restrict__ W1,
                                              const float* __restrict__ W2,
                                              const float* __restrict__ W3,
                                              short* __restrict__ WtBase) {
  const int z = blockIdx.z;
  const float* W = (z == 0) ? W0 : (z == 1) ? W1 : (z == 2) ? W2 : W3;
  short* Wt = WtBase + (size_t)z * EMB * EMB;
  __shared__ short tile[32][33];
  int nT = blockIdx.x * 32, kT = blockIdx.y * 32;
  int tx = threadIdx.x, ty = threadIdx.y;
  #pragma unroll
  for (int i = 0; i < 4; ++i)
    tile[ty + 8*i][tx] = (short)f2bf_fast(W[(size_t)(kT + ty + 8*i) * EMB + nT + tx]);
  __syncthreads();
  #pragma unroll
  for (int i = 0; i < 4; ++i)
    Wt[(size_t)(nT + ty + 8*i) * EMB + kT + tx] = tile[tx][ty + 8*i];
}

// ---------------------------------------------------------------- fused QKV GEMM, 128x64 tiles
// N fused to 3072 (Wt holds Wq^T|Wk^T|Wv^T contiguous). grid (48,32) = 1536 blocks = 6/CU.
__global__ __launch_bounds__(256) void gemm_qkv(const short* __restrict__ A,
                                                const short* __restrict__ Wt,
                                                const float* __restrict__ bq,
                                                const float* __restrict__ bk,
                                                const float* __restrict__ bv,
                                                const float* __restrict__ pos,
                                                short* __restrict__ QKbase,
                                                short* __restrict__ vtOut) {
  const int m0 = blockIdx.y * 128, n0 = blockIdx.x * 64;
  const int z = n0 >> 10;                       // 0=Q 1=K 2=V (64-tile never crosses)
  const float* bias = (z == 0) ? bq : (z == 1 ? bk : bv);

  __shared__ __align__(16) short As[128 * 64];  // 16 KB
  __shared__ __align__(16) short Bs[64 * 64];   // 8 KB

  const int t = threadIdx.x;
  const int lane = t & 63, w = t >> 6;
  const int wm = w >> 1, wn = w & 1;            // wave tile 64m x 32n
  const int quad = lane >> 4, l16 = lane & 15;
  const int lrow8 = lane >> 3, lchunk = lane & 7;
  const int gch = lchunk ^ lrow8;               // swizzled source chunk
  const int sw7 = l16 & 7;

  const short* Arow = A  + (size_t)(m0 + w * 32 + lrow8) * EMB + gch * 8;
  const short* Brow = Wt + (size_t)(n0 + w * 16 + lrow8) * EMB + gch * 8;

  f32x4 acc[4][2] = {};

  for (int k0 = 0; k0 < EMB; k0 += 64) {
    #pragma unroll
    for (int s = 0; s < 4; ++s)
      cp16(Arow + (size_t)(s * 8) * EMB + k0, &As[(w * 32 + s * 8) * 64]);
    #pragma unroll
    for (int s = 0; s < 2; ++s)
      cp16(Brow + (size_t)(s * 8) * EMB + k0, &Bs[(w * 16 + s * 8) * 64]);
    __syncthreads();
    #pragma unroll
    for (int ks = 0; ks < 2; ++ks) {
      const int chv = ((ks << 2) + quad) ^ sw7;
      short8 af[4], bfr[2];
      #pragma unroll
      for (int i = 0; i < 4; ++i)
        af[i] = *(const short8*)&As[(wm * 64 + i * 16 + l16) * 64 + chv * 8];
      #pragma unroll
      for (int j = 0; j < 2; ++j)
        bfr[j] = *(const short8*)&Bs[(wn * 32 + j * 16 + l16) * 64 + chv * 8];
      #pragma unroll
      for (int i = 0; i < 4; ++i)
        #pragma unroll
        for (int j = 0; j < 2; ++j)
          acc[i][j] = __builtin_amdgcn_mfma_f32_16x16x32_bf16(af[i], bfr[j], acc[i][j], 0, 0, 0);
    }
    __syncthreads();
  }

  // epilogue: C row = quad*4+r, col = l16
  #pragma unroll
  for (int i = 0; i < 4; ++i) {
    int mbase = m0 + wm * 64 + i * 16 + quad * 4;
    #pragma unroll
    for (int j = 0; j < 2; ++j) {
      int n = n0 + wn * 32 + j * 16 + l16;
      int nl = n & 1023;
      float bn = bias[nl];
      int d = nl & (HDIM - 1);
      if (z == 2) {
        // write V transposed: [b,h,d,s] so attn stages Vt rows contiguously
        int bh = (mbase >> 10) * NHEAD + (nl >> 6);
        int s = mbase & (SEQ - 1);
        us4 pk;
        #pragma unroll
        for (int r = 0; r < 4; ++r) {
          float v = acc[i][j][r] + bn + pos[(size_t)(mbase + r) * HDIM + d];
          pk[r] = f2bf_fast(v);
        }
        *(us4*)&vtOut[((size_t)bh * HDIM + d) * SEQ + s] = pk;
      } else {
        #pragma unroll
        for (int r = 0; r < 4; ++r) {
          int mm = mbase + r;
          float v = acc[i][j][r] + bn + pos[(size_t)mm * HDIM + d];
          QKbase[(size_t)z * MELEM + (size_t)mm * EMB + nl] = (short)f2bf_fast(v);
        }
      }
    }
  }
}

// ---------------------------------------------------------------- Wo GEMM: 64x64 tiles (4 blocks/CU)
__global__ __launch_bounds__(256) void gemm_wo(const short* __restrict__ A,
                                               const short* __restrict__ Bt,
                                               const float* __restrict__ bias,
                                               float* __restrict__ out) {
  const int m0 = blockIdx.y * 64, n0 = blockIdx.x * 64;

  __shared__ __align__(16) short As[64 * 64];
  __shared__ __align__(16) short Bs[64 * 64];

  const int t = threadIdx.x;
  const int lane = t & 63, w = t >> 6;
  const int wm = w >> 1, wn = w & 1;          // wave tile: 32m x 32n
  const int quad = lane >> 4, l16 = lane & 15;
  const int lrow8 = lane >> 3, lchunk = lane & 7;
  const int gch = lchunk ^ lrow8;
  const int sw7 = l16 & 7;

  const short* Arow = A  + (size_t)(m0 + w * 16 + lrow8) * EMB + gch * 8;
  const short* Brow = Bt + (size_t)(n0 + w * 16 + lrow8) * EMB + gch * 8;

  f32x4 acc[2][2] = {};

  for (int k0 = 0; k0 < EMB; k0 += 64) {
    #pragma unroll
    for (int s = 0; s < 2; ++s) {
      cp16(Arow + (size_t)(s * 8) * EMB + k0, &As[(w * 16 + s * 8) * 64]);
      cp16(Brow + (size_t)(s * 8) * EMB + k0, &Bs[(w * 16 + s * 8) * 64]);
    }
    __syncthreads();
    #pragma unroll
    for (int ks = 0; ks < 2; ++ks) {
      const int chv = ((ks << 2) + quad) ^ sw7;
      short8 af[2], bfr[2];
      #pragma unroll
      for (int i = 0; i < 2; ++i)
        af[i] = *(const short8*)&As[(wm * 32 + i * 16 + l16) * 64 + chv * 8];
      #pragma unroll
      for (int j = 0; j < 2; ++j)
        bfr[j] = *(const short8*)&Bs[(wn * 32 + j * 16 + l16) * 64 + chv * 8];
      #pragma unroll
      for (int i = 0; i < 2; ++i)
        #pragma unroll
        for (int j = 0; j < 2; ++j)
          acc[i][j] = __builtin_amdgcn_mfma_f32_16x16x32_bf16(af[i], bfr[j], acc[i][j], 0, 0, 0);
    }
    __syncthreads();
  }

  #pragma unroll
  for (int i = 0; i < 2; ++i) {
    int mbase = m0 + wm * 32 + i * 16 + quad * 4;
    #pragma unroll
    for (int j = 0; j < 2; ++j) {
      int n = n0 + wn * 32 + j * 16 + l16;
      float bn = bias[n];
      #pragma unroll
      for (int r = 0; r < 4; ++r)
        out[(size_t)(mbase + r) * EMB + n] = acc[i][j][r] + bn;
    }
  }
}

// ---------------------------------------------------------------- flash attention, k-split waves
// No-max softmax (scores bounded) means exp needs no cross-k info -> the k dimension
// can be SPLIT ACROSS WAVES with zero per-tile reduction:
//   QK:  wave w computes scores for q-half (w>>1) x k-half (w&1): B-frag reads 16 -> 8
//   P:   written to BLOCK-shared swizzled Pw; committed by an lgkm-only barrier
//        (full __syncthreads would drain the just-issued K/Im cp16s with zero slack)
//   PV:  wave w accumulates O-partial for q-half (w>>1) over k-slice (w&1) (K=32):
//        V reads 8 -> 4. Pair-sum of O and row-sums once in the epilogue via LDS.
// Per-wave LDS reads/tile: 26 -> 14 b128 (the LDS pipe was the measured floor, R8).
// Phase pipeline (R8) retained: stage K/Im(kt+1) commits at barrier2 (slack exp+PV),
// stage Vt(kt+1) commits at next barrier1 (slack QK).
__global__ __launch_bounds__(256, 4) void attn(const short* __restrict__ Qp,
                                               const short* __restrict__ Kp,
                                               const short* __restrict__ VtG,
                                               const short* __restrict__ Imb,
                                               short* __restrict__ attnA) {
  const int qb = blockIdx.y * 64;
  const int bh = blockIdx.x;
  const int b = bh >> 4, h = bh & 15;
  const int t = threadIdx.x, lane = t & 63, w = t >> 6;   // w: 0..3
  const int quad = lane >> 4, l16 = lane & 15;
  const int lrow8 = lane >> 3, lchunk = lane & 7;
  const int gch = lchunk ^ lrow8;
  const int sw7 = l16 & 7;
  const int qh = w >> 1;    // q-half (QK and PV)
  const int kh = w & 1;     // k-half (QK cols / PV k-slice)

  __shared__ __align__(16) short tiles[3 * 64 * 64];   // K | Im | Vt  (24576 B)
  __shared__ __align__(16) short Pw[64 * 64];          // block-shared P, swizzled (8192 B)

  // Q/Im A-fragments: rows qb + qh*32 + qg*16 + l16
  short8 aq[2][2], aim[2][2];
  #pragma unroll
  for (int qg = 0; qg < 2; ++qg) {
    const int q = qb + qh * 32 + qg * 16 + l16;
    const size_t qoff = ((size_t)(b * SEQ + q)) * EMB + h * HDIM + quad * 8;
    aq [qg][0] = *(const short8*)&Qp [qoff];
    aq [qg][1] = *(const short8*)&Qp [qoff + 32];
    aim[qg][0] = *(const short8*)&Imb[qoff];
    aim[qg][1] = *(const short8*)&Imb[qoff + 32];
  }

  float lr[2][4] = {};      // per-lane partial row sums (wave's k-half only)
  f32x4 o[2][4] = {};       // O partial: q rows qh*32+qg2*16, k-slice kh

  const float SC = 0.03125f * 1.44269504089f;   // /sqrt(1024) * log2(e)
  const size_t kimBase = ((size_t)b * SEQ) * EMB + h * HDIM + gch * 8;
  const size_t vtBase  = ((size_t)bh * HDIM) * SEQ + gch * 8;

  // prologue: stage all of tile 0 (6 cp16 per wave = 24 total = 3 x 8 KB)
  #pragma unroll
  for (int s = 0; s < 6; ++s) {
    const int I = w * 6 + s;
    const int tz = I >> 3;
    const int row = ((I & 7) * 8) + lrow8;
    const short* g;
    if (tz == 0)      g = Kp  + kimBase + (size_t)row * EMB;
    else if (tz == 1) g = Imb + kimBase + (size_t)row * EMB;
    else              g = VtG + vtBase + (size_t)row * SEQ;
    cp16(g, &tiles[I * 512]);
  }
  __syncthreads();

  for (int kt = 0; kt < 16; ++kt) {
    const int kBaseN = (kt + 1) * 64;

    // ---- QK phase: 32 q (qh half) x 32 k (kh half), full K=64
    f32x4 sa[2][2] = {};
    #pragma unroll
    for (int kg = 0; kg < 2; ++kg) {
      const int rowoff = (kh * 32 + kg * 16 + l16) * 64;
      #pragma unroll
      for (int st = 0; st < 2; ++st) {
        const int chv = (((st << 2) + quad) ^ sw7) * 8;
        short8 bk = *(const short8*)&tiles[rowoff + chv];
        short8 bi = *(const short8*)&tiles[4096 + rowoff + chv];
        #pragma unroll
        for (int qg = 0; qg < 2; ++qg) {
          sa[qg][kg] = __builtin_amdgcn_mfma_f32_16x16x32_bf16(aq [qg][st], bk, sa[qg][kg], 0, 0, 0);
          sa[qg][kg] = __builtin_amdgcn_mfma_f32_16x16x32_bf16(aim[qg][st], bi, sa[qg][kg], 0, 0, 0);
        }
      }
    }

    __syncthreads();   // full: QK(kt) reads done; Vt(kt) committed (own-vmcnt drain)

    // ---- stage K/Im(kt+1); commits at barrier2 (slack = exp + PV)
    if (kt != 15) {
      #pragma unroll
      for (int s = 0; s < 4; ++s) {
        const int I = w * 4 + s;            // 0..15
        const int row = ((I & 7) * 8) + lrow8;
        const short* g = ((I >> 3) ? Imb : Kp) + kimBase + (size_t)(kBaseN + row) * EMB;
        cp16(g, &tiles[I * 512]);
      }
    }

    // ---- exp + write P to block-shared swizzled Pw
    // element (row, col): row = qh*32+qg*16+quad*4+r, col = kh*32+kg*16+l16
    // stored chunk = (col>>3) ^ (row&7)  [row&7 == (quad*4+r)&7]
    #pragma unroll
    for (int qg = 0; qg < 2; ++qg)
      #pragma unroll
      for (int kg = 0; kg < 2; ++kg)
        #pragma unroll
        for (int r = 0; r < 4; ++r) {
          float p = __builtin_amdgcn_exp2f(sa[qg][kg][r] * SC);
          lr[qg][r] += p;
          const int row = qh * 32 + qg * 16 + quad * 4 + r;
          const int sch = (kh * 4 + kg * 2 + (l16 >> 3)) ^ ((quad * 4 + r) & 7);
          Pw[row * 64 + sch * 8 + (l16 & 7)] = (short)f2bf_fast(p);
        }

    // lgkm-only barrier: commit P(kt) across waves WITHOUT draining K/Im cp16s in flight
    __asm__ __volatile__("s_waitcnt lgkmcnt(0)\n\ts_barrier" ::: "memory");

    // ---- PV phase: O-partial for 32 q (qh) x 64 d over k-slice kh (K=32)
    short8 ap[2];
    #pragma unroll
    for (int qg2 = 0; qg2 < 2; ++qg2)
      ap[qg2] = *(const short8*)&Pw[(qh * 32 + qg2 * 16 + l16) * 64 +
                                    (((kh * 4 + quad) ^ sw7) * 8)];
    #pragma unroll
    for (int cd = 0; cd < 4; ++cd) {
      short8 bv2 = *(const short8*)&tiles[8192 + (cd * 16 + l16) * 64 +
                                          (((kh * 4 + quad) ^ sw7) * 8)];
      #pragma unroll
      for (int qg2 = 0; qg2 < 2; ++qg2)
        o[qg2][cd] = __builtin_amdgcn_mfma_f32_16x16x32_bf16(ap[qg2], bv2, o[qg2][cd], 0, 0, 0);
    }

    __syncthreads();   // full: PV/P reads done; K/Im(kt+1) committed

    // ---- stage Vt(kt+1); commits at next barrier1 (slack = QK)
    if (kt != 15) {
      #pragma unroll
      for (int s = 0; s < 2; ++s) {
        const int I = 16 + w * 2 + s;       // 16..23
        const int row = ((I & 7) * 8) + lrow8;
        cp16(VtG + vtBase + (size_t)row * SEQ + kBaseN, &tiles[I * 512]);
      }
    }
  }

  // ---------------- epilogue: cross-wave reductions via reused LDS ----------------
  // row-sum halves -> lbuf[row][kh] (Pw region, reads all done)
  float* lbuf = (float*)Pw;
  #pragma unroll
  for (int qg = 0; qg < 2; ++qg)
    #pragma unroll
    for (int r = 0; r < 4; ++r) {
      float s = lr[qg][r];
      #pragma unroll
      for (int msk = 1; msk < 16; msk <<= 1) s += __shfl_xor(s, msk);
      if (l16 == 0) lbuf[(qh * 32 + qg * 16 + quad * 4 + r) * 2 + kh] = s;
    }
  // O partials from kh==1 waves -> fbuf (tiles region, stride 65 to spread banks)
  float* fbuf = (float*)tiles;
  if (kh == 1) {
    #pragma unroll
    for (int qg2 = 0; qg2 < 2; ++qg2)
      #pragma unroll
      for (int cd = 0; cd < 4; ++cd)
        #pragma unroll
        for (int r = 0; r < 4; ++r)
          fbuf[(size_t)(qh * 32 + qg2 * 16 + quad * 4 + r) * 65 + cd * 16 + l16] = o[qg2][cd][r];
  }
  __syncthreads();
  if (kh == 0) {
    #pragma unroll
    for (int qg2 = 0; qg2 < 2; ++qg2)
      #pragma unroll
      for (int r = 0; r < 4; ++r) {
        const int row = qh * 32 + qg2 * 16 + quad * 4 + r;
        float linv = 1.f / (lbuf[row * 2] + lbuf[row * 2 + 1]);
        size_t base = ((size_t)(b * SEQ + qb + row)) * EMB + h * HDIM;
        #pragma unroll
        for (int cd = 0; cd < 4; ++cd) {
          float v = (o[qg2][cd][r] + fbuf[(size_t)row * 65 + cd * 16 + l16]) * linv;
          attnA[base + cd * 16 + l16] = (short)f2bf_fast(v);
        }
      }
  }
}

// ---------------------------------------------------------------- launch
extern "C" void kernel_launch(void* const* d_in, const int* in_sizes, int n_in,
                              void* d_out, int out_size, void* d_ws, size_t ws_size,
                              hipStream_t stream) {
  const float* Re  = (const float*)d_in[0];
  const float* Im  = (const float*)d_in[1];
  const float* pos = (const float*)d_in[2];
  const float* Wq  = (const float*)d_in[3];
  const float* bq  = (const float*)d_in[4];
  const float* Wk  = (const float*)d_in[5];
  const float* bk  = (const float*)d_in[6];
  const float* Wv  = (const float*)d_in[7];
  const float* bv  = (const float*)d_in[8];
  const float* Wo  = (const float*)d_in[9];
  const float* bo  = (const float*)d_in[10];

  short* ws    = (short*)d_ws;
  short* Rebf  = ws;                         // 4M shorts
  short* Imbf  = ws + (size_t)MELEM;         // 4M
  short* Wt    = ws + (size_t)2 * MELEM;     // 4 x 1M (q,k,v,o)
  short* Qp    = ws + (size_t)3 * MELEM;     // Q,K projections + Vt: 3 x 4M
  short* Kp    = Qp + (size_t)MELEM;
  short* VtG   = Qp + (size_t)2 * MELEM;     // V transposed [b,h,d,s]
  short* attnA = ws + (size_t)6 * MELEM;     // 4M

  cvt_bf16<<<dim3(MELEM / 1024, 2), 256, 0, stream>>>(Re, Im, Rebf, Imbf);

  wtrans<<<dim3(32, 32, 4), dim3(32, 8), 0, stream>>>(Wq, Wk, Wv, Wo, Wt);

  // fused Q/K/V projection (+bias +P), bf16 out; V written transposed. N fused to 3072.
  gemm_qkv<<<dim3(3 * EMB / 64, MTOT / 128), 256, 0, stream>>>(
      Rebf, Wt, bq, bk, bv, pos, Qp, VtG);

  // flash attention (x = bh for XCD-local L2 reuse of K/Im/Vt)
  attn<<<dim3(BATCH * NHEAD, SEQ / 64), 256, 0, stream>>>(
      Qp, Kp, VtG, Imbf, attnA);

  // output projection, f32 out, 64x64 tiles for 4 blocks/CU
  gemm_wo<<<dim3(EMB / 64, MTOT / 64), 256, 0, stream>>>(
      attnA, Wt + 3 * EMB * EMB, bo, (float*)d_out);
}